// Round 1
// baseline (375.340 us; speedup 1.0000x reference)
//
#include <hip/hip_runtime.h>
#include <math.h>

// Capsule routing, algebraically restructured so u_hat (256 MB) is never
// materialized. All contractions over u_hat factor through W:
//   v[b,n,c] = sum_i c[b,n,i] u[b,i,c]         (batched GEMM, 537 MFLOP)
//   s[b,n,d] = sum_c v[b,n,c] W[c,n*64+d]      (tiny)
//   o = squash(s)
//   t[b,n,c] = sum_d o[b,n,d] W[c,n*64+d]      (tiny)
//   b[b,n,i] = sum_c t[b,n,c] u[b,i,c]         (batched GEMM, 537 MFLOP)
// Iter 0: b=0 -> c uniform 1/32 -> v0 = colsum(u)/32 (n-independent).

constexpr int Bn = 32;     // batch
constexpr int In = 1024;   // input capsules
constexpr int Cn = 256;    // channels
constexpr int Nn = 32;     // num capsule
constexpr int Dn = 64;     // dim capsule
constexpr int ND = Nn * Dn; // 2048

// ---------------- W [Cn][ND] -> Wt [ND][Cn] (coalesced t-kernel reads) ------
__global__ void k_transpose(const float* __restrict__ W, float* __restrict__ Wt) {
  __shared__ float tile[64][65];
  int x0 = blockIdx.x * 64;  // nd tile
  int y0 = blockIdx.y * 64;  // c tile
  int lx = threadIdx.x & 63;
  int ly = threadIdx.x >> 6;  // 0..3
#pragma unroll
  for (int k = 0; k < 16; ++k) {
    int y = ly + k * 4;
    tile[y][lx] = W[(size_t)(y0 + y) * ND + x0 + lx];
  }
  __syncthreads();
#pragma unroll
  for (int k = 0; k < 16; ++k) {
    int y = ly + k * 4;
    Wt[(size_t)(x0 + y) * Cn + y0 + lx] = tile[lx][y];
  }
}

// ---------------- psu[b][ch][c] = sum over 128 i of u[b,i,c] ----------------
__global__ void k_colsum(const float* __restrict__ u, float* __restrict__ psu) {
  int b = blockIdx.x, ch = blockIdx.y, c = threadIdx.x;
  const float* up = u + ((size_t)(b * In + ch * 128)) * Cn + c;
  float s = 0.f;
#pragma unroll 8
  for (int j = 0; j < 128; ++j) s += up[(size_t)j * Cn];
  psu[(b * 8 + ch) * Cn + c] = s;
}

// ---- s[b,n,d] = sum_c v[b,n,c] W[c,nd]; o = squash(s) over d ---------------
// src holds 8 partial chunks; addr = src + b*bStride + n*nStride + ch*chunkStride + c
__global__ void k_s_squash(const float* __restrict__ src, const float* __restrict__ W,
                           float* __restrict__ o, int bStride, int nStride,
                           int chunkStride, float scale) {
  int bn = blockIdx.x, n = bn & 31, b = bn >> 5;
  __shared__ float vsum[Cn];
  int tid = threadIdx.x;
  const float* p = src + (size_t)b * bStride + (size_t)n * nStride + tid;
  float s = 0.f;
#pragma unroll
  for (int ch = 0; ch < 8; ++ch) s += p[(size_t)ch * chunkStride];
  vsum[tid] = s * scale;
  __syncthreads();
  if (tid < Dn) {
    const float* wp = W + n * Dn + tid;
    float acc = 0.f;
#pragma unroll 8
    for (int c = 0; c < Cn; ++c) acc += vsum[c] * wp[(size_t)c * ND];
    float sq = acc * acc;
#pragma unroll
    for (int off = 32; off > 0; off >>= 1) sq += __shfl_xor(sq, off, 64);
    o[bn * Dn + tid] = acc / sqrtf(sq + 1e-7f);
  }
}

// ---------------- t[b,n,c] = sum_d o[b,n,d] Wt[nd][c] -----------------------
__global__ void k_t(const float* __restrict__ o, const float* __restrict__ Wt,
                    float* __restrict__ tb) {
  int bn = blockIdx.x, n = bn & 31;
  __shared__ float ol[Dn];
  int tid = threadIdx.x;
  if (tid < Dn) ol[tid] = o[bn * Dn + tid];
  __syncthreads();
  const float* wp = Wt + (size_t)(n * Dn) * Cn + tid;
  float acc = 0.f;
#pragma unroll 8
  for (int d = 0; d < Dn; ++d) acc += ol[d] * wp[(size_t)d * Cn];
  tb[bn * Cn + tid] = acc;
}

// ---- bb[b,n,i] = sum_c t[b,n,c] u[b,i,c]; then softmax over n -> cbuf ------
// Block = (b, i-tile of 64). 256 threads: lane i = tid&63, n-group = tid>>6.
__global__ void k_bupd_softmax(const float* __restrict__ tb, const float* __restrict__ u,
                               float* __restrict__ cbuf) {
  int b = blockIdx.x;
  int it0 = blockIdx.y * 64;
  int tid = threadIdx.x;
  __shared__ float u_l[64][65];   // stride 65: scalar lane reads, conflict-free
  __shared__ float t_l[32][68];   // stride 68: 16B-aligned float4 broadcasts
  __shared__ float bb_l[32][65];
  int i = tid & 63;
  int wg = tid >> 6;  // 0..3 -> 8 n's each
  float acc[8];
#pragma unroll
  for (int k = 0; k < 8; ++k) acc[k] = 0.f;
  for (int cc = 0; cc < 4; ++cc) {
    int c0 = cc * 64;
#pragma unroll
    for (int k = 0; k < 16; ++k) {  // stage u 64x64 (coalesced)
      int idx = tid + k * 256;
      int ii = idx >> 6, c = idx & 63;
      u_l[ii][c] = u[((size_t)(b * In + it0 + ii)) * Cn + c0 + c];
    }
#pragma unroll
    for (int k = 0; k < 8; ++k) {   // stage t 32x64 (coalesced)
      int idx = tid + k * 256;
      int n = idx >> 6, c = idx & 63;
      t_l[n][c] = tb[(size_t)(b * Nn + n) * Cn + c0 + c];
    }
    __syncthreads();
    for (int c = 0; c < 64; c += 4) {
      float u0 = u_l[i][c], u1 = u_l[i][c + 1], u2 = u_l[i][c + 2], u3 = u_l[i][c + 3];
#pragma unroll
      for (int k = 0; k < 8; ++k) {
        const float4 t4 = *(const float4*)&t_l[wg * 8 + k][c];
        acc[k] += t4.x * u0 + t4.y * u1 + t4.z * u2 + t4.w * u3;
      }
    }
    __syncthreads();
  }
#pragma unroll
  for (int k = 0; k < 8; ++k) bb_l[wg * 8 + k][i] = acc[k];
  __syncthreads();
  if (tid < 64) {  // softmax over n for 64 i's
    float m = -1e30f;
#pragma unroll
    for (int n = 0; n < Nn; ++n) m = fmaxf(m, bb_l[n][tid]);
    float e[Nn];
    float ssum = 0.f;
#pragma unroll
    for (int n = 0; n < Nn; ++n) { e[n] = __expf(bb_l[n][tid] - m); ssum += e[n]; }
    float inv = 1.f / ssum;
#pragma unroll
    for (int n = 0; n < Nn; ++n)
      cbuf[((size_t)(b * Nn + n)) * In + it0 + tid] = e[n] * inv;
  }
}

// ---- pv[b,ich,n,c] = sum over 128 i of c[b,n,i] u[b,i,c] -------------------
__global__ void k_vpart(const float* __restrict__ cbuf, const float* __restrict__ u,
                        float* __restrict__ pv) {
  int b = blockIdx.x;
  int ich = blockIdx.y;
  int i0 = ich * 128;
  int tid = threadIdx.x;  // c index
  __shared__ float c_l[32][128];
#pragma unroll
  for (int k = 0; k < 16; ++k) {
    int idx = tid + k * 256;
    int n = idx >> 7, ii = idx & 127;
    c_l[n][ii] = cbuf[((size_t)(b * Nn + n)) * In + i0 + ii];
  }
  __syncthreads();
  float acc[32];
#pragma unroll
  for (int n = 0; n < 32; ++n) acc[n] = 0.f;
  const float* up = u + ((size_t)(b * In + i0)) * Cn + tid;
  for (int ii = 0; ii < 128; ii += 4) {
    float u0 = up[(size_t)(ii + 0) * Cn], u1 = up[(size_t)(ii + 1) * Cn];
    float u2 = up[(size_t)(ii + 2) * Cn], u3 = up[(size_t)(ii + 3) * Cn];
#pragma unroll
    for (int n = 0; n < 32; ++n) {
      const float4 c4 = *(const float4*)&c_l[n][ii];
      acc[n] += c4.x * u0 + c4.y * u1 + c4.z * u2 + c4.w * u3;
    }
  }
#pragma unroll
  for (int n = 0; n < 32; ++n)
    pv[((size_t)((b * 8 + ich) * Nn + n)) * Cn + tid] = acc[n];
}

extern "C" void kernel_launch(void* const* d_in, const int* in_sizes, int n_in,
                              void* d_out, int out_size, void* d_ws, size_t ws_size,
                              hipStream_t stream) {
  (void)in_sizes; (void)n_in; (void)out_size; (void)ws_size;
  const float* u = (const float*)d_in[0];   // (32,1024,256)
  const float* W = (const float*)d_in[1];   // (256,2048)
  float* out = (float*)d_out;               // (32,32,64) = 65536 floats
  float* ws = (float*)d_ws;
  // workspace layout (floats): total ~3.99M floats = 15.3 MB
  float* Wt   = ws;                  // 2048*256      = 524288
  float* psu  = Wt + 524288;         // 32*8*256      = 65536
  float* tb   = psu + 65536;         // 32*32*256     = 262144
  float* cbuf = tb + 262144;         // 32*32*1024    = 1048576
  float* pv   = cbuf + 1048576;      // 32*8*32*256   = 2097152

  k_transpose<<<dim3(32, 4), 256, 0, stream>>>(W, Wt);
  k_colsum<<<dim3(32, 8), 256, 0, stream>>>(u, psu);
  // iter 0: c uniform 1/32 -> v0 = colsum/32 (nStride=0)
  k_s_squash<<<1024, 256, 0, stream>>>(psu, W, out, 2048, 0, 256, 1.0f / 32.0f);
  k_t<<<1024, 256, 0, stream>>>(out, Wt, tb);
  k_bupd_softmax<<<dim3(32, 16), 256, 0, stream>>>(tb, u, cbuf);
  // iter 1
  k_vpart<<<dim3(32, 8), 256, 0, stream>>>(cbuf, u, pv);
  k_s_squash<<<1024, 256, 0, stream>>>(pv, W, out, 65536, 256, 8192, 1.0f);
  k_t<<<1024, 256, 0, stream>>>(out, Wt, tb);
  k_bupd_softmax<<<dim3(32, 16), 256, 0, stream>>>(tb, u, cbuf);
  // iter 2 (final)
  k_vpart<<<dim3(32, 8), 256, 0, stream>>>(cbuf, u, pv);
  k_s_squash<<<1024, 256, 0, stream>>>(pv, W, out, 65536, 256, 8192, 1.0f);
}

// Round 2
// 261.440 us; speedup vs baseline: 1.4357x; 1.4357x over previous
//
#include <hip/hip_runtime.h>
#include <math.h>

// Capsule routing, u_hat never materialized (factors through W):
//   v[b,n,c] = sum_i c[b,n,i] u[b,i,c]
//   s[b,n,d] = sum_c v[b,n,c] W[c,n*64+d];  o = squash(s)
//   t[b,n,c] = sum_d o[b,n,d] W[c,n*64+d]
//   b[b,n,i] = sum_c t[b,n,c] u[b,i,c]   (replaced each iter, not accumulated)
// Iter 0: b=0 -> c uniform 1/32 -> v0 = colsum(u)/32.
//
// R2 restructure: fuse (b-update + softmax + v-partials) into k_route — one
// pass over u per routing iteration, softmax stays in LDS (no cbuf global
// round-trip); fuse (s+squash+t) into k_sst. 512-thread route blocks for
// 16 waves/CU (R1 was 8 waves/CU, latency-bound at VALUBusy=11%).

constexpr int Bn = 32;      // batch
constexpr int In = 1024;    // input capsules
constexpr int Cn = 256;     // channels
constexpr int Nn = 32;      // num capsule
constexpr int Dn = 64;      // dim capsule
constexpr int ND = Nn * Dn; // 2048

// ---------------- W [Cn][ND] -> Wt [ND][Cn] ---------------------------------
__global__ void k_transpose(const float* __restrict__ W, float* __restrict__ Wt) {
  __shared__ float tile[64][65];
  int x0 = blockIdx.x * 64;  // nd tile
  int y0 = blockIdx.y * 64;  // c tile
  int lx = threadIdx.x & 63;
  int ly = threadIdx.x >> 6;  // 0..3
#pragma unroll
  for (int k = 0; k < 16; ++k) {
    int y = ly + k * 4;
    tile[y][lx] = W[(size_t)(y0 + y) * ND + x0 + lx];
  }
  __syncthreads();
#pragma unroll
  for (int k = 0; k < 16; ++k) {
    int y = ly + k * 4;
    Wt[(size_t)(x0 + y) * Cn + y0 + lx] = tile[lx][y];
  }
}

// ---------------- psu[b][ch][c] = sum over 32 i of u[b,i,c] -----------------
// 1024 blocks (4/CU) for latency hiding; lane-coalesced column sums.
__global__ void k_colsum(const float* __restrict__ u, float* __restrict__ psu) {
  int b = blockIdx.x, ch = blockIdx.y, c = threadIdx.x;
  const float* up = u + ((size_t)(b * In + ch * 32)) * Cn + c;
  float s = 0.f;
#pragma unroll 8
  for (int j = 0; j < 32; ++j) s += up[(size_t)j * Cn];
  psu[(b * 32 + ch) * Cn + c] = s;
}

// ---- fused: v-reduce -> s -> squash -> t (and final output write) ----------
// Block (b,n), 256 threads (c-lanes).
__global__ void k_sst(const float* __restrict__ src, int count, int bStride,
                      int nStride, int chunkStride, float scale,
                      const float* __restrict__ W, const float* __restrict__ Wt,
                      float* __restrict__ tb, float* __restrict__ outp, int writeT) {
  int bn = blockIdx.x, b = bn >> 5, n = bn & 31;
  int tid = threadIdx.x;  // c
  __shared__ float vs[Cn];
  __shared__ float ol[Dn];
  const float* p = src + (size_t)b * bStride + (size_t)n * nStride + tid;
  float s = 0.f;
#pragma unroll 4
  for (int ch = 0; ch < count; ++ch) s += p[(size_t)ch * chunkStride];
  vs[tid] = s * scale;
  __syncthreads();
  if (tid < Dn) {
    // s[d] = sum_c vs[c] * W[c, n*64+d] : lanes=d coalesced 256B per c-step
    const float* wp = W + (size_t)n * Dn + tid;
    float a = 0.f;
#pragma unroll 8
    for (int cix = 0; cix < Cn; ++cix) a += vs[cix] * wp[(size_t)cix * ND];
    float sq = a * a;
#pragma unroll
    for (int off = 32; off > 0; off >>= 1) sq += __shfl_xor(sq, off, 64);
    float o = a / sqrtf(sq + 1e-7f);
    ol[tid] = o;
    if (outp) outp[bn * Dn + tid] = o;
  }
  __syncthreads();
  if (writeT) {
    // t[c] = sum_d ol[d] * Wt[n*64+d, c] : lanes=c coalesced 1KB per d-step
    const float* wtp = Wt + (size_t)(n * Dn) * Cn + tid;
    float a = 0.f;
#pragma unroll 8
    for (int d = 0; d < Dn; ++d) a += ol[d] * wtp[(size_t)d * Cn];
    tb[bn * Cn + tid] = a;
  }
}

// ---- fused routing step: bb = t.u^T -> softmax over n -> pv partials -------
// Block (b, it): 64 i's, 512 threads (8 waves).
// Phase A: bb[n,i] = sum_c t[n,c] u[i,c]   (wave w -> 4 n's, lane -> i)
// Softmax over n per i (LDS-local, in place in bb_l).
// Phase B: pv[n,c] = sum_{i in tile} c[n,i] u[i,c]  (wave g -> 4 n's, lane -> c)
__global__ __launch_bounds__(512) void k_route(const float* __restrict__ tb,
                                               const float* __restrict__ u,
                                               float* __restrict__ pv) {
  int b = blockIdx.x, it = blockIdx.y, it0 = it * 64;
  int tid = threadIdx.x;
  __shared__ float u_l[64][65];   // stride 65: row (lanes=c) stride1; col (lanes=i) 2-way free
  __shared__ float t_l[32][68];   // stride 68: 16B-aligned float4 broadcast rows
  __shared__ float bb_l[32][65];  // bb, then c (softmax result) in place
  int lane = tid & 63;
  int w = tid >> 6;  // 0..7
  float acc[4] = {0.f, 0.f, 0.f, 0.f};
  for (int cc = 0; cc < 4; ++cc) {
    int c0 = cc * 64;
#pragma unroll
    for (int k = 0; k < 8; ++k) {  // stage u 64x64 chunk, coalesced
      int idx = tid + k * 512;
      int ii = idx >> 6, c = idx & 63;
      u_l[ii][c] = u[((size_t)(b * In + it0 + ii)) * Cn + c0 + c];
    }
#pragma unroll
    for (int k = 0; k < 4; ++k) {  // stage t 32x64 chunk, coalesced
      int idx = tid + k * 512;
      int n = idx >> 6, c = idx & 63;
      t_l[n][c] = tb[(size_t)(b * Nn + n) * Cn + c0 + c];
    }
    __syncthreads();
    for (int c = 0; c < 64; c += 4) {
      float u0 = u_l[lane][c], u1 = u_l[lane][c + 1];
      float u2 = u_l[lane][c + 2], u3 = u_l[lane][c + 3];
#pragma unroll
      for (int k = 0; k < 4; ++k) {
        const float4 tv = *(const float4*)&t_l[w * 4 + k][c];
        acc[k] += tv.x * u0 + tv.y * u1 + tv.z * u2 + tv.w * u3;
      }
    }
    __syncthreads();
  }
#pragma unroll
  for (int k = 0; k < 4; ++k) bb_l[w * 4 + k][lane] = acc[k];
  __syncthreads();
  if (tid < 64) {  // softmax over n for this i, in place
    float m = -1e30f;
#pragma unroll
    for (int n = 0; n < Nn; ++n) m = fmaxf(m, bb_l[n][tid]);
    float e[Nn];
    float ssum = 0.f;
#pragma unroll
    for (int n = 0; n < Nn; ++n) { e[n] = __expf(bb_l[n][tid] - m); ssum += e[n]; }
    float inv = 1.f / ssum;
#pragma unroll
    for (int n = 0; n < Nn; ++n) bb_l[n][tid] = e[n] * inv;
  }
  __syncthreads();
  // Phase B: lane=c within chunk, wave g -> 4 n's
  int g = w;
  for (int cc = 0; cc < 4; ++cc) {
    int c0 = cc * 64;
#pragma unroll
    for (int k = 0; k < 8; ++k) {  // re-stage u chunk (L2-hot)
      int idx = tid + k * 512;
      int ii = idx >> 6, cx = idx & 63;
      u_l[ii][cx] = u[((size_t)(b * In + it0 + ii)) * Cn + c0 + cx];
    }
    __syncthreads();
    float a2[4] = {0.f, 0.f, 0.f, 0.f};
#pragma unroll 8
    for (int ii = 0; ii < 64; ++ii) {
      float uv = u_l[ii][lane];
#pragma unroll
      for (int k = 0; k < 4; ++k) a2[k] += bb_l[g * 4 + k][ii] * uv;
    }
#pragma unroll
    for (int k = 0; k < 4; ++k)
      pv[((size_t)((b * 16 + it) * Nn + g * 4 + k)) * Cn + c0 + lane] = a2[k];
    __syncthreads();
  }
}

extern "C" void kernel_launch(void* const* d_in, const int* in_sizes, int n_in,
                              void* d_out, int out_size, void* d_ws, size_t ws_size,
                              hipStream_t stream) {
  (void)in_sizes; (void)n_in; (void)out_size; (void)ws_size;
  const float* u = (const float*)d_in[0];   // (32,1024,256)
  const float* W = (const float*)d_in[1];   // (256,2048)
  float* out = (float*)d_out;               // (32,32,64)
  float* ws = (float*)d_ws;
  // workspace (floats): pv 4194304 (psu 262144 overlaid) + Wt 524288 + tb 262144
  float* pv  = ws;                // 32*16*32*256 = 4194304 (16 MB)
  float* psu = ws;                // overlays pv: 32*32*256 = 262144 (dead before pv written)
  float* Wt  = ws + 4194304;      // 2048*256 = 524288
  float* tbb = ws + 4718592;      // 32*32*256 = 262144

  k_transpose<<<dim3(32, 4), 256, 0, stream>>>(W, Wt);
  k_colsum<<<dim3(32, 32), 256, 0, stream>>>(u, psu);
  // iter 0: c uniform 1/32 -> v0 = colsum/32 (nStride=0)
  k_sst<<<1024, 256, 0, stream>>>(psu, 32, 8192, 0, 256, 1.0f / 32.0f, W, Wt, tbb, nullptr, 1);
  // iter 1
  k_route<<<dim3(32, 16), 512, 0, stream>>>(tbb, u, pv);
  k_sst<<<1024, 256, 0, stream>>>(pv, 16, 131072, 256, 8192, 1.0f, W, Wt, tbb, nullptr, 1);
  // iter 2 (final: write out, skip t)
  k_route<<<dim3(32, 16), 512, 0, stream>>>(tbb, u, pv);
  k_sst<<<1024, 256, 0, stream>>>(pv, 16, 131072, 256, 8192, 1.0f, W, Wt, tbb, out, 0);
}